// Round 2
// baseline (308.651 us; speedup 1.0000x reference)
//
#include <hip/hip_runtime.h>

#define NUSERS  6041
#define NMOVIES 3953
#define EMB     32
#define NGEN    18
#define H1N     64
#define H2N     32
#define H3N     16

typedef __bf16 bf16_t;
typedef bf16_t bf16x8 __attribute__((ext_vector_type(8)));
typedef bf16_t bf16x4 __attribute__((ext_vector_type(4)));
typedef float  f32x4  __attribute__((ext_vector_type(4)));
typedef float  f32x8  __attribute__((ext_vector_type(8)));

__device__ __forceinline__ f32x4 mfma16(bf16x8 a, bf16x8 b, f32x4 c) {
    return __builtin_amdgcn_mfma_f32_16x16x32_bf16(a, b, c, 0, 0, 0);
}
__device__ __forceinline__ bf16x8 cvt8(f32x8 v) {
    bf16x8 o;
    #pragma unroll
    for (int i = 0; i < 8; ++i) o[i] = (bf16_t)v[i];
    return o;
}

#define L1STRIDE 68
#define L2STRIDE 36
#define RSTRIDE  28
#define RBUFSZ   (16 * RSTRIDE)

// rest row layout (bf16, 24 elems = 48 B, matches W1 rest k-order):
//   [0]=gender [1]=age [2]=occupation [3..20]=genres[0..17]
//   [21]=0 (k=85 wide slot, filled at runtime) [22]=1.0 (k=86 bias slot) [23]=0
#define RESTW 24
#define PREPROWS 512

#define TAB_U4   (NUSERS * EMB / 4)            // 48328
#define TAB_M4   (NMOVIES * EMB / 4)           // 31624
#define TAB4TOT  (TAB_U4 + TAB_M4)             // 79952

// ---------------------------------------------------------------------------
// prep: pack rest features to bf16 rows + convert embedding tables to bf16
// ---------------------------------------------------------------------------
__device__ __forceinline__ void pack_rest_row(const float* __restrict__ x, // 18 genres
                                              float gg, float aa, float oo,
                                              bf16_t* __restrict__ op)
{
    bf16x8 c0, c1, c2;
    c0[0] = (bf16_t)gg;   c0[1] = (bf16_t)aa;   c0[2] = (bf16_t)oo;
    c0[3] = (bf16_t)x[0]; c0[4] = (bf16_t)x[1]; c0[5] = (bf16_t)x[2];
    c0[6] = (bf16_t)x[3]; c0[7] = (bf16_t)x[4];
    #pragma unroll
    for (int j = 0; j < 8; ++j) c1[j] = (bf16_t)x[5 + j];
    #pragma unroll
    for (int j = 0; j < 5; ++j) c2[j] = (bf16_t)x[13 + j];
    c2[5] = (bf16_t)0.0f;
    c2[6] = (bf16_t)1.0f;   // k=86 constant-1 feature -> layer-1 bias row in B1f
    c2[7] = (bf16_t)0.0f;
    *(bf16x8*)(op)      = c0;
    *(bf16x8*)(op + 8)  = c1;
    *(bf16x8*)(op + 16) = c2;
}

__global__ __launch_bounds__(256)
void prep_all(const float* __restrict__ gender,
              const float* __restrict__ age,
              const float* __restrict__ occupation,
              const float* __restrict__ genres,
              const float* __restrict__ user_table,
              const float* __restrict__ movie_table,
              bf16_t* __restrict__ rest,
              bf16_t* __restrict__ utab,
              bf16_t* __restrict__ mtab,
              int n)
{
    const int t  = threadIdx.x;
    const int b  = blockIdx.x;
    const int gB = (n + PREPROWS - 1) / PREPROWS;

    if (b < gB) {
        const int r0 = b * PREPROWS;
        if ((n & 1) == 0) {
            // fast path: n*18 divisible by 4 -> coalesced float4 stage via LDS
            __shared__ float gbuf[PREPROWS * NGEN];          // 36864 B
            const float4* gsrc = (const float4*)genres;
            const int totF4  = (n * NGEN) >> 2;
            const int f4base = (r0 >> 1) * 9;                // r0*18/4
            #pragma unroll
            for (int s = 0; s < 9; ++s) {
                const int gi = t + s * 256;
                int idx = f4base + gi;
                if (idx > totF4 - 1) idx = totF4 - 1;
                *(float4*)(gbuf + gi * 4) = gsrc[idx];
            }
            __syncthreads();
            #pragma unroll
            for (int rr = 0; rr < 2; ++rr) {
                const int lr = t + rr * 256;                 // 18*lr stride: ~2-4 way banks
                const int r  = r0 + lr;
                if (r < n) {
                    float x[NGEN];
                    #pragma unroll
                    for (int c = 0; c < NGEN; ++c) x[c] = gbuf[lr * NGEN + c];
                    pack_rest_row(x, gender[r], age[r], occupation[r],
                                  rest + (size_t)r * RESTW);
                }
            }
        } else {
            // cold generic path
            for (int rr = 0; rr < 2; ++rr) {
                const int r = r0 + t + rr * 256;
                if (r < n) {
                    const float* gr = genres + (size_t)r * NGEN;
                    float x[NGEN];
                    #pragma unroll
                    for (int c = 0; c < NGEN; ++c) x[c] = gr[c];
                    pack_rest_row(x, gender[r], age[r], occupation[r],
                                  rest + (size_t)r * RESTW);
                }
            }
        }
    } else {
        // embedding tables -> bf16
        const int u = (b - gB) * 256 + t;
        if (u < TAB4TOT) {
            if (u < TAB_U4) {
                float4 v = *(const float4*)(user_table + (size_t)u * 4);
                bf16x4 o; o[0]=(bf16_t)v.x; o[1]=(bf16_t)v.y; o[2]=(bf16_t)v.z; o[3]=(bf16_t)v.w;
                *(bf16x4*)(utab + (size_t)u * 4) = o;
            } else {
                const int w = u - TAB_U4;
                float4 v = *(const float4*)(movie_table + (size_t)w * 4);
                bf16x4 o; o[0]=(bf16_t)v.x; o[1]=(bf16_t)v.y; o[2]=(bf16_t)v.z; o[3]=(bf16_t)v.w;
                *(bf16x4*)(mtab + (size_t)w * 4) = o;
            }
        }
    }
}

// ---------------------------------------------------------------------------
// main: operand-swapped MFMA chain, batch pinned to lane&15 through all
// layers -> zero LDS, zero inter-layer shuffles, 2-op final reduce.
// ---------------------------------------------------------------------------
__global__ __launch_bounds__(256, 4)
void wd_fwd_main(const int*   __restrict__ user_ids,
                 const int*   __restrict__ movie_ids,
                 const float* __restrict__ wide_W,
                 const float* __restrict__ wide_b,
                 const float* __restrict__ W1,
                 const float* __restrict__ b1,
                 const float* __restrict__ W2,
                 const float* __restrict__ b2,
                 const float* __restrict__ W3,
                 const float* __restrict__ b3,
                 const float* __restrict__ W4,
                 const float* __restrict__ b4,
                 const bf16_t* __restrict__ utab,
                 const bf16_t* __restrict__ mtab,
                 const bf16_t* __restrict__ rest,
                 float*       __restrict__ out,
                 int n)
{
    const int lane = threadIdx.x & 63;
    const int m    = lane & 15;
    const int quad = lane >> 4;

    // ---------------- weight fragments (A-operands of the swapped MFMAs) ----
    // B1f tile nt: A[row=m][k=quad*8+j] = W1^T[nt*16+m][k]; k=86 row = b1 (bias)
    bf16x8 B1f[3][4];
    #pragma unroll
    for (int kt = 0; kt < 3; ++kt)
        #pragma unroll
        for (int nt = 0; nt < 4; ++nt) {
            bf16x8 f;
            #pragma unroll
            for (int j = 0; j < 8; ++j) {
                const int k = kt * 32 + quad * 8 + j;
                float v;
                if (k < 85)       v = W1[k * H1N + nt * 16 + m];
                else if (k == 86) v = b1[nt * 16 + m];
                else              v = 0.0f;
                f[j] = (bf16_t)v;
            }
            B1f[kt][nt] = f;
        }
    // wide row: A[row=0][k] = w_rest (k<85), 1.0 at k=85
    bf16x8 Bwf;
    {
        const float* wr = wide_W + NUSERS + NMOVIES;
        #pragma unroll
        for (int j = 0; j < 8; ++j) {
            const int k = 64 + quad * 8 + j;
            float v = 0.0f;
            if (m == 0) { if (k < 85) v = wr[k - 64]; else if (k == 85) v = 1.0f; }
            Bwf[j] = (bf16_t)v;
        }
    }
    // B2f: k-rows permuted so the layer-2 B-operand is lane-local:
    //   slot (kt,quad,j) carries physical h1 unit u = (2kt + (j>>2))*16 + quad*4 + (j&3)
    bf16x8 B2f[2][2];
    #pragma unroll
    for (int kt = 0; kt < 2; ++kt)
        #pragma unroll
        for (int nt = 0; nt < 2; ++nt) {
            bf16x8 f;
            #pragma unroll
            for (int j = 0; j < 8; ++j) {
                const int u = (2 * kt + (j >> 2)) * 16 + quad * 4 + (j & 3);
                f[j] = (bf16_t)W2[u * H2N + nt * 16 + m];
            }
            B2f[kt][nt] = f;
        }
    // B3f: same permutation trick for layer 3 (h2 units)
    bf16x8 B3f;
    #pragma unroll
    for (int j = 0; j < 8; ++j) {
        const int u = (j >> 2) * 16 + quad * 4 + (j & 3);
        B3f[j] = (bf16_t)W3[u * H3N + m];
    }

    // per-reg biases (unit index = <tile>*16 + quad*4 + r)
    f32x4 bias2[2], bias3, w4f;
    bias2[0] = *(const f32x4*)(b2 + quad * 4);
    bias2[1] = *(const f32x4*)(b2 + 16 + quad * 4);
    bias3    = *(const f32x4*)(b3 + quad * 4);
    w4f      = *(const f32x4*)(W4 + quad * 4);
    const float b4v = b4[0];
    const float wb0 = wide_b[0];

    const int ntiles = (n + 15) >> 4;
    const int gwave  = (blockIdx.x * blockDim.x + threadIdx.x) >> 6;
    const int nwaves = (gridDim.x * blockDim.x) >> 6;
    int niter = 0;
    if (gwave < ntiles) niter = (ntiles - gwave + nwaves - 1) / nwaves;
    if (niter == 0) return;            // no barriers anywhere in this kernel

    int t_c = gwave;
    int t_n = t_c + nwaves; if (t_n >= ntiles) t_n = t_c;

    // prologue: current tile fully loaded; next tile's ids loaded
    int rc = t_c * 16 + m; if (rc >= n) rc = n - 1;
    int uid_c = user_ids[rc], mid_c = movie_ids[rc];
    bf16x8 A0c = *(const bf16x8*)(utab + (size_t)uid_c * EMB + quad * 8);
    bf16x8 A1c = *(const bf16x8*)(mtab + (size_t)mid_c * EMB + quad * 8);
    bf16x8 A2c;
    #pragma unroll
    for (int j = 0; j < 8; ++j) A2c[j] = (bf16_t)0.0f;
    if (quad < 3) A2c = *(const bf16x8*)(rest + (size_t)rc * RESTW + quad * 8);
    float wuc = 0.0f, wmc = 0.0f;
    if (quad == 2) { wuc = wide_W[uid_c]; wmc = wide_W[NUSERS + mid_c]; }
    int rn = t_n * 16 + m; if (rn >= n) rn = n - 1;
    int uid_n = user_ids[rn], mid_n = movie_ids[rn];

    for (int i = 0; i < niter; ++i) {
        // ---- 1. prefetch next tile (gathers use ids loaded >=1 iter ago) ----
        const bool more = (i + 1 < niter);
        bf16x8 A0n = A0c, A1n = A1c, A2n;
        #pragma unroll
        for (int j = 0; j < 8; ++j) A2n[j] = (bf16_t)0.0f;
        float wun = wuc, wmn = wmc;
        int uid_n2 = uid_n, mid_n2 = mid_n;
        int t_n2 = t_n;
        if (more) {
            A0n = *(const bf16x8*)(utab + (size_t)uid_n * EMB + quad * 8);
            A1n = *(const bf16x8*)(mtab + (size_t)mid_n * EMB + quad * 8);
            int rx = t_n * 16 + m; if (rx >= n) rx = n - 1;
            if (quad < 3) A2n = *(const bf16x8*)(rest + (size_t)rx * RESTW + quad * 8);
            wun = 0.0f; wmn = 0.0f;
            if (quad == 2) { wun = wide_W[uid_n]; wmn = wide_W[NUSERS + mid_n]; }
            t_n2 = t_n + nwaves; if (t_n2 >= ntiles) t_n2 = t_n;
            int r2 = t_n2 * 16 + m; if (r2 >= n) r2 = n - 1;
            uid_n2 = user_ids[r2]; mid_n2 = movie_ids[r2];
        }

        // ---- 2. compute tile t_c (everything register-resident) ----
        bf16x8 A2 = A2c;
        if (quad == 2) A2[5] = (bf16_t)(wuc + wmc + wb0);   // k=85 wide feature

        f32x4 accw = mfma16(Bwf, A2, (f32x4){0.f, 0.f, 0.f, 0.f});

        // layer 1: h1^T tiles; lane(m,q) reg r = h1[nt*16+q*4+r][batch=m]
        f32x4 acc[4];
        #pragma unroll
        for (int nt = 0; nt < 4; ++nt) {
            f32x4 c = {0.f, 0.f, 0.f, 0.f};
            c = mfma16(B1f[2][nt], A2,  c);     // rest + bias(k=86)
            c = mfma16(B1f[1][nt], A1c, c);     // movie emb
            c = mfma16(B1f[0][nt], A0c, c);     // user emb
            acc[nt] = c;
        }

        // L1 -> L2 glue: relu + bf16 pack, pure registers (W2 rows permuted)
        bf16x8 AL2[2];
        #pragma unroll
        for (int kt = 0; kt < 2; ++kt) {
            bf16x8 f;
            #pragma unroll
            for (int r = 0; r < 4; ++r) {
                f[r]     = (bf16_t)fmaxf(acc[2 * kt][r],     0.0f);
                f[4 + r] = (bf16_t)fmaxf(acc[2 * kt + 1][r], 0.0f);
            }
            AL2[kt] = f;
        }

        // layer 2: h2^T; lane(m,q) reg r = h2[nt2*16+q*4+r][batch=m]
        f32x4 acc2[2];
        #pragma unroll
        for (int nt = 0; nt < 2; ++nt) {
            f32x4 c = bias2[nt];
            c = mfma16(B2f[0][nt], AL2[0], c);
            c = mfma16(B2f[1][nt], AL2[1], c);
            acc2[nt] = c;
        }

        // L2 -> L3 glue
        bf16x8 AL3;
        #pragma unroll
        for (int r = 0; r < 4; ++r) {
            AL3[r]     = (bf16_t)fmaxf(acc2[0][r], 0.0f);
            AL3[4 + r] = (bf16_t)fmaxf(acc2[1][r], 0.0f);
        }

        // layer 3: h3^T; lane(m,q) reg r = h3[q*4+r][batch=m]
        f32x4 acc3 = mfma16(B3f, AL3, bias3);

        // layer 4 + reduce across quads (2 shuffles)
        float p = fmaxf(acc3[0], 0.0f) * w4f[0]
                + fmaxf(acc3[1], 0.0f) * w4f[1]
                + fmaxf(acc3[2], 0.0f) * w4f[2]
                + fmaxf(acc3[3], 0.0f) * w4f[3];
        p += __shfl_xor(p, 16, 64);
        p += __shfl_xor(p, 32, 64);
        if (lane < 16) {                         // quad 0 holds accw row 0
            const int orow = (t_c << 4) + lane;
            if (orow < n) {
                const float zv = p + accw[0] + b4v;
                out[orow] = 1.0f / (1.0f + __expf(-zv));
            }
        }

        // ---- 3. rotate pipeline ----
        if (more) {
            A0c = A0n; A1c = A1n; A2c = A2n;
            wuc = wun; wmc = wmn;
            uid_n = uid_n2; mid_n = mid_n2;
            t_c = t_n; t_n = t_n2;
        }
    }
}

// ---------------------------------------------------------------------------
// fallback: previous verified kernel (used only if workspace is too small)
// ---------------------------------------------------------------------------
struct Pref {
    float4 u0, u1, m0, m1;
    float  wu, wm;
};

__global__ __launch_bounds__(256)
void wd_fwd_pipe(const int*   __restrict__ user_ids,
                 const int*   __restrict__ movie_ids,
                 const float* __restrict__ gender,
                 const float* __restrict__ age,
                 const float* __restrict__ occupation,
                 const float* __restrict__ genres,
                 const float* __restrict__ wide_W,
                 const float* __restrict__ wide_b,
                 const float* __restrict__ user_table,
                 const float* __restrict__ movie_table,
                 const float* __restrict__ W1,
                 const float* __restrict__ b1,
                 const float* __restrict__ W2,
                 const float* __restrict__ b2,
                 const float* __restrict__ W3,
                 const float* __restrict__ b3,
                 const float* __restrict__ W4,
                 const float* __restrict__ b4,
                 float*       __restrict__ out,
                 int n)
{
    const int lane = threadIdx.x & 63;
    const int wib  = threadIdx.x >> 6;
    const int m    = lane & 15;
    const int quad = lane >> 4;

    __shared__ float lds_rest[4][2 * RBUFSZ];
    __shared__ float lds1[4][16 * L1STRIDE];
    __shared__ float lds2[4][16 * L2STRIDE];
    float* __restrict__ rbase = lds_rest[wib];
    float* __restrict__ L1p   = lds1[wib];
    float* __restrict__ L2p   = lds2[wib];

    for (int k = lane; k < 2 * RBUFSZ; k += 64) rbase[k] = 0.0f;

    bf16x8 B1f[3][4];
    #pragma unroll
    for (int kt = 0; kt < 3; ++kt)
        #pragma unroll
        for (int nt = 0; nt < 4; ++nt) {
            bf16x8 f;
            #pragma unroll
            for (int j = 0; j < 8; ++j) {
                const int k  = kt * 32 + quad * 8 + j;
                const float v = (k < 85) ? W1[k * H1N + nt * 16 + m] : 0.0f;
                f[j] = (bf16_t)v;
            }
            B1f[kt][nt] = f;
        }
    bf16x8 Bwf;
    {
        const float* wr = wide_W + NUSERS + NMOVIES;
        #pragma unroll
        for (int j = 0; j < 8; ++j) {
            const int k = 64 + quad * 8 + j;
            float v = 0.0f;
            if (m == 0) { if (k < 85) v = wr[k - 64]; else if (k == 85) v = 1.0f; }
            Bwf[j] = (bf16_t)v;
        }
    }
    bf16x8 B2f[2][2];
    #pragma unroll
    for (int kt = 0; kt < 2; ++kt)
        #pragma unroll
        for (int nt = 0; nt < 2; ++nt) {
            bf16x8 f;
            #pragma unroll
            for (int j = 0; j < 8; ++j)
                f[j] = (bf16_t)W2[(kt * 32 + quad * 8 + j) * H2N + nt * 16 + m];
            B2f[kt][nt] = f;
        }
    bf16x8 B3f;
    #pragma unroll
    for (int j = 0; j < 8; ++j) B3f[j] = (bf16_t)W3[(quad * 8 + j) * H3N + m];

    float bias1[4], bias2[2];
    #pragma unroll
    for (int nt = 0; nt < 4; ++nt) bias1[nt] = b1[nt * 16 + m];
    #pragma unroll
    for (int nt = 0; nt < 2; ++nt) bias2[nt] = b2[nt * 16 + m];
    const float bias3 = b3[m];
    const float w4v   = W4[m];
    const float b4v   = b4[0];
    const float wb0   = wide_b[0];

    const int ntiles = (n + 15) >> 4;
    const int gwave  = blockIdx.x * 4 + wib;
    const int nwaves = gridDim.x * 4;
    int niter = 0;
    if (gwave < ntiles) niter = (ntiles - gwave + nwaves - 1) / nwaves;
    const long gmax = (long)n * NGEN - 1;

#define LOAD_IDS(tt, U, M) { int rr = (tt) * 16 + m; rr = rr < n ? rr : n - 1; \
                             U = user_ids[rr]; M = movie_ids[rr]; }
#define LOAD_GENRES(tt, G, SC) { \
    const long gb = (long)(tt) * (16 * NGEN); \
    _Pragma("unroll") \
    for (int r = 0; r < 4; ++r) { long idx = gb + lane + r * 64; \
        idx = idx < gmax ? idx : gmax; G[r] = genres[idx]; } \
    { long idx = gb + lane + 256; idx = idx < gmax ? idx : gmax; \
      G[4] = (lane < 32) ? genres[idx] : 0.0f; } \
    { int rr = (tt) * 16 + m; rr = rr < n ? rr : n - 1; \
      const float* sp = (quad == 0) ? gender : (quad == 1) ? age : occupation; \
      SC = (quad < 3) ? sp[rr] : 0.0f; } }
#define WRITE_RBUF(B, G, SC) { \
    float* rb_ = rbase + (B) * RBUFSZ; \
    _Pragma("unroll") \
    for (int r = 0; r < 4; ++r) { int gi = lane + r * 64; int rw = gi / NGEN; \
        int cl = gi - rw * NGEN; rb_[rw * RSTRIDE + 3 + cl] = G[r]; } \
    if (lane < 32) { int gi = lane + 256; int rw = gi / NGEN; int cl = gi - rw * NGEN; \
        rb_[rw * RSTRIDE + 3 + cl] = G[4]; } \
    if (quad < 3) rb_[m * RSTRIDE + quad] = SC; }
#define ISSUE_GATHER(UID, MID, P) { \
    const float4* up_ = (const float4*)(user_table + (size_t)(UID) * EMB + quad * 8); \
    P.u0 = up_[0]; P.u1 = up_[1]; \
    const float4* mp_ = (const float4*)(movie_table + (size_t)(MID) * EMB + quad * 8); \
    P.m0 = mp_[0]; P.m1 = mp_[1]; \
    P.wu = wide_W[UID]; P.wm = wide_W[NUSERS + (MID)]; }

    if (niter > 0) {
        int t_c = gwave;
        int t_n = t_c + nwaves; if (t_n >= ntiles) t_n = t_c;

        int uid_c, mid_c, uid_n, mid_n, uid_n2, mid_n2;
        float gg_c[5], sc_c, gg_n[5], sc_n;
        Pref P_c, P_n;

        LOAD_IDS(t_c, uid_c, mid_c);
        LOAD_GENRES(t_c, gg_c, sc_c);
        ISSUE_GATHER(uid_c, mid_c, P_c);
        LOAD_IDS(t_n, uid_n, mid_n);
        WRITE_RBUF(0, gg_c, sc_c);
        uid_n2 = uid_n; mid_n2 = mid_n;
        int buf = 0;

        for (int i = 0; i < niter; ++i) {
            const float* rb = rbase + buf * RBUFSZ;
            const float4* sA = (const float4*)(rb + m * RSTRIDE + quad * 8);
            float4 a2a = sA[0], a2b = sA[1];

            const bool more = (i + 1 < niter);
            int t_n2 = t_n;
            if (more) {
                LOAD_GENRES(t_n, gg_n, sc_n);
                ISSUE_GATHER(uid_n, mid_n, P_n);
                t_n2 = t_n + nwaves; if (t_n2 >= ntiles) t_n2 = t_n;
                LOAD_IDS(t_n2, uid_n2, mid_n2);
            }

            const int base = t_c << 4;
            f32x8 vf;
            vf[0]=P_c.u0.x; vf[1]=P_c.u0.y; vf[2]=P_c.u0.z; vf[3]=P_c.u0.w;
            vf[4]=P_c.u1.x; vf[5]=P_c.u1.y; vf[6]=P_c.u1.z; vf[7]=P_c.u1.w;
            bf16x8 A0 = cvt8(vf);
            vf[0]=P_c.m0.x; vf[1]=P_c.m0.y; vf[2]=P_c.m0.z; vf[3]=P_c.m0.w;
            vf[4]=P_c.m1.x; vf[5]=P_c.m1.y; vf[6]=P_c.m1.z; vf[7]=P_c.m1.w;
            bf16x8 A1 = cvt8(vf);
            vf[0]=a2a.x; vf[1]=a2a.y; vf[2]=a2a.z; vf[3]=a2a.w;
            vf[4]=a2b.x; vf[5]=a2b.y; vf[6]=a2b.z; vf[7]=a2b.w;
            if (quad == 2) vf[5] = P_c.wu + P_c.wm + wb0;
            bf16x8 A2 = cvt8(vf);

            f32x4 accw = mfma16(A2, Bwf, (f32x4){0.f, 0.f, 0.f, 0.f});

            f32x4 acc[4];
            #pragma unroll
            for (int nt = 0; nt < 4; ++nt) {
                f32x4 c = {bias1[nt], bias1[nt], bias1[nt], bias1[nt]};
                c = mfma16(A0, B1f[0][nt], c);
                c = mfma16(A1, B1f[1][nt], c);
                c = mfma16(A2, B1f[2][nt], c);
                acc[nt] = c;
            }
            #pragma unroll
            for (int nt = 0; nt < 4; ++nt)
                #pragma unroll
                for (int r = 0; r < 4; ++r)
                    L1p[(quad * 4 + r) * L1STRIDE + nt * 16 + m] = fmaxf(acc[nt][r], 0.0f);

            bf16x8 AL2[2];
            #pragma unroll
            for (int kt = 0; kt < 2; ++kt) {
                const float4* s = (const float4*)(L1p + m * L1STRIDE + kt * 32 + quad * 8);
                float4 a = s[0], b = s[1];
                f32x8 t8; t8[0]=a.x; t8[1]=a.y; t8[2]=a.z; t8[3]=a.w;
                t8[4]=b.x; t8[5]=b.y; t8[6]=b.z; t8[7]=b.w;
                AL2[kt] = cvt8(t8);
            }

            f32x4 acc2[2];
            #pragma unroll
            for (int nt = 0; nt < 2; ++nt) {
                f32x4 c = {bias2[nt], bias2[nt], bias2[nt], bias2[nt]};
                c = mfma16(AL2[0], B2f[0][nt], c);
                c = mfma16(AL2[1], B2f[1][nt], c);
                acc2[nt] = c;
            }
            #pragma unroll
            for (int nt = 0; nt < 2; ++nt)
                #pragma unroll
                for (int r = 0; r < 4; ++r)
                    L2p[(quad * 4 + r) * L2STRIDE + nt * 16 + m] = fmaxf(acc2[nt][r], 0.0f);

            bf16x8 AL3;
            {
                const float4* s = (const float4*)(L2p + m * L2STRIDE + quad * 8);
                float4 a = s[0], b = s[1];
                f32x8 t8; t8[0]=a.x; t8[1]=a.y; t8[2]=a.z; t8[3]=a.w;
                t8[4]=b.x; t8[5]=b.y; t8[6]=b.z; t8[7]=b.w;
                AL3 = cvt8(t8);
            }

            f32x4 acc3 = mfma16(AL3, B3f, (f32x4){bias3, bias3, bias3, bias3});

            float t0 = fmaxf(acc3[0], 0.0f) * w4v + accw[0];
            float t1 = fmaxf(acc3[1], 0.0f) * w4v + accw[1];
            float t2 = fmaxf(acc3[2], 0.0f) * w4v + accw[2];
            float t3 = fmaxf(acc3[3], 0.0f) * w4v + accw[3];
            #pragma unroll
            for (int off = 1; off < 16; off <<= 1) {
                t0 += __shfl_xor(t0, off, 64);
                t1 += __shfl_xor(t1, off, 64);
                t2 += __shfl_xor(t2, off, 64);
                t3 += __shfl_xor(t3, off, 64);
            }
            if (m < 4) {
                float zv = t0;
                zv = (m == 1) ? t1 : zv;
                zv = (m == 2) ? t2 : zv;
                zv = (m == 3) ? t3 : zv;
                zv += b4v;
                const int orow = base + quad * 4 + m;
                if (orow < n) out[orow] = 1.0f / (1.0f + __expf(-zv));
            }

            if (more) {
                WRITE_RBUF(buf ^ 1, gg_n, sc_n);
                P_c = P_n;
                uid_c = uid_n; mid_c = mid_n;
                uid_n = uid_n2; mid_n = mid_n2;
                t_c = t_n; t_n = t_n2;
                buf ^= 1;
            }
        }
    }
#undef LOAD_IDS
#undef LOAD_GENRES
#undef WRITE_RBUF
#undef ISSUE_GATHER
}

extern "C" void kernel_launch(void* const* d_in, const int* in_sizes, int n_in,
                              void* d_out, int out_size, void* d_ws, size_t ws_size,
                              hipStream_t stream)
{
    const int*   user_ids   = (const int*)  d_in[0];
    const int*   movie_ids  = (const int*)  d_in[1];
    const float* gender     = (const float*)d_in[2];
    const float* age        = (const float*)d_in[3];
    const float* occupation = (const float*)d_in[4];
    const float* genres     = (const float*)d_in[5];
    const float* wide_W     = (const float*)d_in[6];
    const float* wide_b     = (const float*)d_in[7];
    const float* user_table = (const float*)d_in[8];
    const float* movie_table= (const float*)d_in[9];
    const float* W1         = (const float*)d_in[10];
    const float* b1         = (const float*)d_in[11];
    const float* W2         = (const float*)d_in[12];
    const float* b2         = (const float*)d_in[13];
    const float* W3         = (const float*)d_in[14];
    const float* b3         = (const float*)d_in[15];
    const float* W4         = (const float*)d_in[16];
    const float* b4         = (const float*)d_in[17];
    float*       out        = (float*)d_out;

    const int n = in_sizes[0];

    // workspace layout: utab | mtab | rest (all 256B-aligned)
    const size_t utab_bytes = ((size_t)NUSERS  * EMB * 2 + 255) & ~(size_t)255;
    const size_t mtab_bytes = ((size_t)NMOVIES * EMB * 2 + 255) & ~(size_t)255;
    const size_t rest_bytes = (size_t)n * RESTW * 2;
    const size_t need = utab_bytes + mtab_bytes + rest_bytes;

    if (d_ws != nullptr && ws_size >= need) {
        bf16_t* utab = (bf16_t*)d_ws;
        bf16_t* mtab = (bf16_t*)((char*)d_ws + utab_bytes);
        bf16_t* rest = (bf16_t*)((char*)d_ws + utab_bytes + mtab_bytes);

        const int gB      = (n + PREPROWS - 1) / PREPROWS;
        const int tblocks = (TAB4TOT + 255) / 256;
        prep_all<<<gB + tblocks, 256, 0, stream>>>(gender, age, occupation, genres,
                                                   user_table, movie_table,
                                                   rest, utab, mtab, n);
        wd_fwd_main<<<1024, 256, 0, stream>>>(user_ids, movie_ids, wide_W, wide_b,
                                              W1, b1, W2, b2, W3, b3, W4, b4,
                                              utab, mtab, rest, out, n);
    } else {
        wd_fwd_pipe<<<1024, 256, 0, stream>>>(user_ids, movie_ids, gender, age, occupation,
                                              genres, wide_W, wide_b, user_table, movie_table,
                                              W1, b1, W2, b2, W3, b3, W4, b4, out, n);
    }
}

// Round 3
// 217.459 us; speedup vs baseline: 1.4194x; 1.4194x over previous
//
#include <hip/hip_runtime.h>

#define NUSERS  6041
#define NMOVIES 3953
#define EMB     32
#define NGEN    18
#define H1N     64
#define H2N     32
#define H3N     16

typedef __bf16 bf16_t;
typedef bf16_t bf16x8 __attribute__((ext_vector_type(8)));
typedef bf16_t bf16x4 __attribute__((ext_vector_type(4)));
typedef float  f32x4  __attribute__((ext_vector_type(4)));
typedef float  f32x8  __attribute__((ext_vector_type(8)));

__device__ __forceinline__ f32x4 mfma16(bf16x8 a, bf16x8 b, f32x4 c) {
    return __builtin_amdgcn_mfma_f32_16x16x32_bf16(a, b, c, 0, 0, 0);
}
__device__ __forceinline__ bf16x8 cvt8(f32x8 v) {
    bf16x8 o;
    #pragma unroll
    for (int i = 0; i < 8; ++i) o[i] = (bf16_t)v[i];
    return o;
}

#define L1STRIDE 68
#define L2STRIDE 36
#define RSTRIDE  28
#define RBUFSZ   (16 * RSTRIDE)

// rest row layout (bf16, 24 elems = 48 B, matches W1 rest k-order):
//   [0]=gender [1]=age [2]=occupation [3..20]=genres[0..17]
//   [21]=0 (k=85 wide slot, filled at runtime) [22]=1.0 (k=86 bias slot) [23]=0
#define RESTW 24
#define PREPROWS 512

#define TAB_U4   (NUSERS * EMB / 4)            // 48328
#define TAB_M4   (NMOVIES * EMB / 4)           // 31624
#define TAB4TOT  (TAB_U4 + TAB_M4)             // 79952

// ---------------------------------------------------------------------------
// prep: pack rest features to bf16 rows + convert embedding tables to bf16
// ---------------------------------------------------------------------------
__device__ __forceinline__ void pack_rest_row(const float* __restrict__ x, // 18 genres
                                              float gg, float aa, float oo,
                                              bf16_t* __restrict__ op)
{
    bf16x8 c0, c1, c2;
    c0[0] = (bf16_t)gg;   c0[1] = (bf16_t)aa;   c0[2] = (bf16_t)oo;
    c0[3] = (bf16_t)x[0]; c0[4] = (bf16_t)x[1]; c0[5] = (bf16_t)x[2];
    c0[6] = (bf16_t)x[3]; c0[7] = (bf16_t)x[4];
    #pragma unroll
    for (int j = 0; j < 8; ++j) c1[j] = (bf16_t)x[5 + j];
    #pragma unroll
    for (int j = 0; j < 5; ++j) c2[j] = (bf16_t)x[13 + j];
    c2[5] = (bf16_t)0.0f;
    c2[6] = (bf16_t)1.0f;   // k=86 constant-1 feature -> layer-1 bias row in B1f
    c2[7] = (bf16_t)0.0f;
    *(bf16x8*)(op)      = c0;
    *(bf16x8*)(op + 8)  = c1;
    *(bf16x8*)(op + 16) = c2;
}

__global__ __launch_bounds__(256)
void prep_all(const float* __restrict__ gender,
              const float* __restrict__ age,
              const float* __restrict__ occupation,
              const float* __restrict__ genres,
              const float* __restrict__ user_table,
              const float* __restrict__ movie_table,
              bf16_t* __restrict__ rest,
              bf16_t* __restrict__ utab,
              bf16_t* __restrict__ mtab,
              int n)
{
    const int t  = threadIdx.x;
    const int b  = blockIdx.x;
    const int gB = (n + PREPROWS - 1) / PREPROWS;

    if (b < gB) {
        const int r0 = b * PREPROWS;
        if ((n & 1) == 0) {
            // fast path: n*18 divisible by 4 -> coalesced float4 stage via LDS
            __shared__ float gbuf[PREPROWS * NGEN];          // 36864 B
            const float4* gsrc = (const float4*)genres;
            const int totF4  = (n * NGEN) >> 2;
            const int f4base = (r0 >> 1) * 9;                // r0*18/4
            #pragma unroll
            for (int s = 0; s < 9; ++s) {
                const int gi = t + s * 256;
                int idx = f4base + gi;
                if (idx > totF4 - 1) idx = totF4 - 1;
                *(float4*)(gbuf + gi * 4) = gsrc[idx];
            }
            __syncthreads();
            #pragma unroll
            for (int rr = 0; rr < 2; ++rr) {
                const int lr = t + rr * 256;                 // 18*lr stride: ~2-4 way banks
                const int r  = r0 + lr;
                if (r < n) {
                    float x[NGEN];
                    #pragma unroll
                    for (int c = 0; c < NGEN; ++c) x[c] = gbuf[lr * NGEN + c];
                    pack_rest_row(x, gender[r], age[r], occupation[r],
                                  rest + (size_t)r * RESTW);
                }
            }
        } else {
            // cold generic path
            for (int rr = 0; rr < 2; ++rr) {
                const int r = r0 + t + rr * 256;
                if (r < n) {
                    const float* gr = genres + (size_t)r * NGEN;
                    float x[NGEN];
                    #pragma unroll
                    for (int c = 0; c < NGEN; ++c) x[c] = gr[c];
                    pack_rest_row(x, gender[r], age[r], occupation[r],
                                  rest + (size_t)r * RESTW);
                }
            }
        }
    } else {
        // embedding tables -> bf16
        const int u = (b - gB) * 256 + t;
        if (u < TAB4TOT) {
            if (u < TAB_U4) {
                float4 v = *(const float4*)(user_table + (size_t)u * 4);
                bf16x4 o; o[0]=(bf16_t)v.x; o[1]=(bf16_t)v.y; o[2]=(bf16_t)v.z; o[3]=(bf16_t)v.w;
                *(bf16x4*)(utab + (size_t)u * 4) = o;
            } else {
                const int w = u - TAB_U4;
                float4 v = *(const float4*)(movie_table + (size_t)w * 4);
                bf16x4 o; o[0]=(bf16_t)v.x; o[1]=(bf16_t)v.y; o[2]=(bf16_t)v.z; o[3]=(bf16_t)v.w;
                *(bf16x4*)(mtab + (size_t)w * 4) = o;
            }
        }
    }
}

// ---------------------------------------------------------------------------
// main: operand-swapped MFMA chain, batch pinned to lane&15 through all
// layers -> zero LDS, zero inter-layer shuffles, 2-op final reduce.
// Register-resident model (~170 VGPR live) -> launch_bounds(256,2):
// VGPR cap 256 (no spill), >=2 blocks/CU. (256,4) capped at 64 VGPR and
// spilled ~380 MB/dispatch to scratch -- never cap below the working set.
// ---------------------------------------------------------------------------
__global__ __launch_bounds__(256, 2)
void wd_fwd_main(const int*   __restrict__ user_ids,
                 const int*   __restrict__ movie_ids,
                 const float* __restrict__ wide_W,
                 const float* __restrict__ wide_b,
                 const float* __restrict__ W1,
                 const float* __restrict__ b1,
                 const float* __restrict__ W2,
                 const float* __restrict__ b2,
                 const float* __restrict__ W3,
                 const float* __restrict__ b3,
                 const float* __restrict__ W4,
                 const float* __restrict__ b4,
                 const bf16_t* __restrict__ utab,
                 const bf16_t* __restrict__ mtab,
                 const bf16_t* __restrict__ rest,
                 float*       __restrict__ out,
                 int n)
{
    const int lane = threadIdx.x & 63;
    const int m    = lane & 15;
    const int quad = lane >> 4;

    // ---------------- weight fragments (A-operands of the swapped MFMAs) ----
    // B1f tile nt: A[row=m][k=quad*8+j] = W1^T[nt*16+m][k]; k=86 row = b1 (bias)
    bf16x8 B1f[3][4];
    #pragma unroll
    for (int kt = 0; kt < 3; ++kt)
        #pragma unroll
        for (int nt = 0; nt < 4; ++nt) {
            bf16x8 f;
            #pragma unroll
            for (int j = 0; j < 8; ++j) {
                const int k = kt * 32 + quad * 8 + j;
                float v;
                if (k < 85)       v = W1[k * H1N + nt * 16 + m];
                else if (k == 86) v = b1[nt * 16 + m];
                else              v = 0.0f;
                f[j] = (bf16_t)v;
            }
            B1f[kt][nt] = f;
        }
    // wide row: A[row=0][k] = w_rest (k<85), 1.0 at k=85
    bf16x8 Bwf;
    {
        const float* wr = wide_W + NUSERS + NMOVIES;
        #pragma unroll
        for (int j = 0; j < 8; ++j) {
            const int k = 64 + quad * 8 + j;
            float v = 0.0f;
            if (m == 0) { if (k < 85) v = wr[k - 64]; else if (k == 85) v = 1.0f; }
            Bwf[j] = (bf16_t)v;
        }
    }
    // B2f: k-rows permuted so the layer-2 B-operand is lane-local:
    //   slot (kt,quad,j) carries physical h1 unit u = (2kt + (j>>2))*16 + quad*4 + (j&3)
    bf16x8 B2f[2][2];
    #pragma unroll
    for (int kt = 0; kt < 2; ++kt)
        #pragma unroll
        for (int nt = 0; nt < 2; ++nt) {
            bf16x8 f;
            #pragma unroll
            for (int j = 0; j < 8; ++j) {
                const int u = (2 * kt + (j >> 2)) * 16 + quad * 4 + (j & 3);
                f[j] = (bf16_t)W2[u * H2N + nt * 16 + m];
            }
            B2f[kt][nt] = f;
        }
    // B3f: same permutation trick for layer 3 (h2 units)
    bf16x8 B3f;
    #pragma unroll
    for (int j = 0; j < 8; ++j) {
        const int u = (j >> 2) * 16 + quad * 4 + (j & 3);
        B3f[j] = (bf16_t)W3[u * H3N + m];
    }

    // per-reg biases (unit index = <tile>*16 + quad*4 + r)
    f32x4 bias2[2], bias3, w4f;
    bias2[0] = *(const f32x4*)(b2 + quad * 4);
    bias2[1] = *(const f32x4*)(b2 + 16 + quad * 4);
    bias3    = *(const f32x4*)(b3 + quad * 4);
    w4f      = *(const f32x4*)(W4 + quad * 4);
    const float b4v = b4[0];
    const float wb0 = wide_b[0];

    const int ntiles = (n + 15) >> 4;
    const int gwave  = (blockIdx.x * blockDim.x + threadIdx.x) >> 6;
    const int nwaves = (gridDim.x * blockDim.x) >> 6;
    int niter = 0;
    if (gwave < ntiles) niter = (ntiles - gwave + nwaves - 1) / nwaves;
    if (niter == 0) return;            // no barriers anywhere in this kernel

    int t_c = gwave;
    int t_n = t_c + nwaves; if (t_n >= ntiles) t_n = t_c;

    // prologue: current tile fully loaded; next tile's ids loaded
    int rc = t_c * 16 + m; if (rc >= n) rc = n - 1;
    int uid_c = user_ids[rc], mid_c = movie_ids[rc];
    bf16x8 A0c = *(const bf16x8*)(utab + (size_t)uid_c * EMB + quad * 8);
    bf16x8 A1c = *(const bf16x8*)(mtab + (size_t)mid_c * EMB + quad * 8);
    bf16x8 A2c;
    #pragma unroll
    for (int j = 0; j < 8; ++j) A2c[j] = (bf16_t)0.0f;
    if (quad < 3) A2c = *(const bf16x8*)(rest + (size_t)rc * RESTW + quad * 8);
    float wuc = 0.0f, wmc = 0.0f;
    if (quad == 2) { wuc = wide_W[uid_c]; wmc = wide_W[NUSERS + mid_c]; }
    int rn = t_n * 16 + m; if (rn >= n) rn = n - 1;
    int uid_n = user_ids[rn], mid_n = movie_ids[rn];

    for (int i = 0; i < niter; ++i) {
        // ---- 1. prefetch next tile (gathers use ids loaded >=1 iter ago) ----
        const bool more = (i + 1 < niter);
        bf16x8 A0n = A0c, A1n = A1c, A2n;
        #pragma unroll
        for (int j = 0; j < 8; ++j) A2n[j] = (bf16_t)0.0f;
        float wun = wuc, wmn = wmc;
        int uid_n2 = uid_n, mid_n2 = mid_n;
        int t_n2 = t_n;
        if (more) {
            A0n = *(const bf16x8*)(utab + (size_t)uid_n * EMB + quad * 8);
            A1n = *(const bf16x8*)(mtab + (size_t)mid_n * EMB + quad * 8);
            int rx = t_n * 16 + m; if (rx >= n) rx = n - 1;
            if (quad < 3) A2n = *(const bf16x8*)(rest + (size_t)rx * RESTW + quad * 8);
            wun = 0.0f; wmn = 0.0f;
            if (quad == 2) { wun = wide_W[uid_n]; wmn = wide_W[NUSERS + mid_n]; }
            t_n2 = t_n + nwaves; if (t_n2 >= ntiles) t_n2 = t_n;
            int r2 = t_n2 * 16 + m; if (r2 >= n) r2 = n - 1;
            uid_n2 = user_ids[r2]; mid_n2 = movie_ids[r2];
        }

        // ---- 2. compute tile t_c (everything register-resident) ----
        bf16x8 A2 = A2c;
        if (quad == 2) A2[5] = (bf16_t)(wuc + wmc + wb0);   // k=85 wide feature

        f32x4 accw = mfma16(Bwf, A2, (f32x4){0.f, 0.f, 0.f, 0.f});

        // layer 1: h1^T tiles; lane(m,q) reg r = h1[nt*16+q*4+r][batch=m]
        f32x4 acc[4];
        #pragma unroll
        for (int nt = 0; nt < 4; ++nt) {
            f32x4 c = {0.f, 0.f, 0.f, 0.f};
            c = mfma16(B1f[2][nt], A2,  c);     // rest + bias(k=86)
            c = mfma16(B1f[1][nt], A1c, c);     // movie emb
            c = mfma16(B1f[0][nt], A0c, c);     // user emb
            acc[nt] = c;
        }

        // L1 -> L2 glue: relu + bf16 pack, pure registers (W2 rows permuted)
        bf16x8 AL2[2];
        #pragma unroll
        for (int kt = 0; kt < 2; ++kt) {
            bf16x8 f;
            #pragma unroll
            for (int r = 0; r < 4; ++r) {
                f[r]     = (bf16_t)fmaxf(acc[2 * kt][r],     0.0f);
                f[4 + r] = (bf16_t)fmaxf(acc[2 * kt + 1][r], 0.0f);
            }
            AL2[kt] = f;
        }

        // layer 2: h2^T; lane(m,q) reg r = h2[nt2*16+q*4+r][batch=m]
        f32x4 acc2[2];
        #pragma unroll
        for (int nt = 0; nt < 2; ++nt) {
            f32x4 c = bias2[nt];
            c = mfma16(B2f[0][nt], AL2[0], c);
            c = mfma16(B2f[1][nt], AL2[1], c);
            acc2[nt] = c;
        }

        // L2 -> L3 glue
        bf16x8 AL3;
        #pragma unroll
        for (int r = 0; r < 4; ++r) {
            AL3[r]     = (bf16_t)fmaxf(acc2[0][r], 0.0f);
            AL3[4 + r] = (bf16_t)fmaxf(acc2[1][r], 0.0f);
        }

        // layer 3: h3^T; lane(m,q) reg r = h3[q*4+r][batch=m]
        f32x4 acc3 = mfma16(B3f, AL3, bias3);

        // layer 4 + reduce across quads (2 shuffles)
        float p = fmaxf(acc3[0], 0.0f) * w4f[0]
                + fmaxf(acc3[1], 0.0f) * w4f[1]
                + fmaxf(acc3[2], 0.0f) * w4f[2]
                + fmaxf(acc3[3], 0.0f) * w4f[3];
        p += __shfl_xor(p, 16, 64);
        p += __shfl_xor(p, 32, 64);
        if (lane < 16) {                         // quad 0 reg 0 holds wide row
            const int orow = (t_c << 4) + lane;
            if (orow < n) {
                const float zv = p + accw[0] + b4v;
                out[orow] = 1.0f / (1.0f + __expf(-zv));
            }
        }

        // ---- 3. rotate pipeline ----
        if (more) {
            A0c = A0n; A1c = A1n; A2c = A2n;
            wuc = wun; wmc = wmn;
            uid_n = uid_n2; mid_n = mid_n2;
            t_c = t_n; t_n = t_n2;
        }
    }
}

// ---------------------------------------------------------------------------
// fallback: previous verified kernel (used only if workspace is too small)
// ---------------------------------------------------------------------------
struct Pref {
    float4 u0, u1, m0, m1;
    float  wu, wm;
};

__global__ __launch_bounds__(256)
void wd_fwd_pipe(const int*   __restrict__ user_ids,
                 const int*   __restrict__ movie_ids,
                 const float* __restrict__ gender,
                 const float* __restrict__ age,
                 const float* __restrict__ occupation,
                 const float* __restrict__ genres,
                 const float* __restrict__ wide_W,
                 const float* __restrict__ wide_b,
                 const float* __restrict__ user_table,
                 const float* __restrict__ movie_table,
                 const float* __restrict__ W1,
                 const float* __restrict__ b1,
                 const float* __restrict__ W2,
                 const float* __restrict__ b2,
                 const float* __restrict__ W3,
                 const float* __restrict__ b3,
                 const float* __restrict__ W4,
                 const float* __restrict__ b4,
                 float*       __restrict__ out,
                 int n)
{
    const int lane = threadIdx.x & 63;
    const int wib  = threadIdx.x >> 6;
    const int m    = lane & 15;
    const int quad = lane >> 4;

    __shared__ float lds_rest[4][2 * RBUFSZ];
    __shared__ float lds1[4][16 * L1STRIDE];
    __shared__ float lds2[4][16 * L2STRIDE];
    float* __restrict__ rbase = lds_rest[wib];
    float* __restrict__ L1p   = lds1[wib];
    float* __restrict__ L2p   = lds2[wib];

    for (int k = lane; k < 2 * RBUFSZ; k += 64) rbase[k] = 0.0f;

    bf16x8 B1f[3][4];
    #pragma unroll
    for (int kt = 0; kt < 3; ++kt)
        #pragma unroll
        for (int nt = 0; nt < 4; ++nt) {
            bf16x8 f;
            #pragma unroll
            for (int j = 0; j < 8; ++j) {
                const int k  = kt * 32 + quad * 8 + j;
                const float v = (k < 85) ? W1[k * H1N + nt * 16 + m] : 0.0f;
                f[j] = (bf16_t)v;
            }
            B1f[kt][nt] = f;
        }
    bf16x8 Bwf;
    {
        const float* wr = wide_W + NUSERS + NMOVIES;
        #pragma unroll
        for (int j = 0; j < 8; ++j) {
            const int k = 64 + quad * 8 + j;
            float v = 0.0f;
            if (m == 0) { if (k < 85) v = wr[k - 64]; else if (k == 85) v = 1.0f; }
            Bwf[j] = (bf16_t)v;
        }
    }
    bf16x8 B2f[2][2];
    #pragma unroll
    for (int kt = 0; kt < 2; ++kt)
        #pragma unroll
        for (int nt = 0; nt < 2; ++nt) {
            bf16x8 f;
            #pragma unroll
            for (int j = 0; j < 8; ++j)
                f[j] = (bf16_t)W2[(kt * 32 + quad * 8 + j) * H2N + nt * 16 + m];
            B2f[kt][nt] = f;
        }
    bf16x8 B3f;
    #pragma unroll
    for (int j = 0; j < 8; ++j) B3f[j] = (bf16_t)W3[(quad * 8 + j) * H3N + m];

    float bias1[4], bias2[2];
    #pragma unroll
    for (int nt = 0; nt < 4; ++nt) bias1[nt] = b1[nt * 16 + m];
    #pragma unroll
    for (int nt = 0; nt < 2; ++nt) bias2[nt] = b2[nt * 16 + m];
    const float bias3 = b3[m];
    const float w4v   = W4[m];
    const float b4v   = b4[0];
    const float wb0   = wide_b[0];

    const int ntiles = (n + 15) >> 4;
    const int gwave  = blockIdx.x * 4 + wib;
    const int nwaves = gridDim.x * 4;
    int niter = 0;
    if (gwave < ntiles) niter = (ntiles - gwave + nwaves - 1) / nwaves;
    const long gmax = (long)n * NGEN - 1;

#define LOAD_IDS(tt, U, M) { int rr = (tt) * 16 + m; rr = rr < n ? rr : n - 1; \
                             U = user_ids[rr]; M = movie_ids[rr]; }
#define LOAD_GENRES(tt, G, SC) { \
    const long gb = (long)(tt) * (16 * NGEN); \
    _Pragma("unroll") \
    for (int r = 0; r < 4; ++r) { long idx = gb + lane + r * 64; \
        idx = idx < gmax ? idx : gmax; G[r] = genres[idx]; } \
    { long idx = gb + lane + 256; idx = idx < gmax ? idx : gmax; \
      G[4] = (lane < 32) ? genres[idx] : 0.0f; } \
    { int rr = (tt) * 16 + m; rr = rr < n ? rr : n - 1; \
      const float* sp = (quad == 0) ? gender : (quad == 1) ? age : occupation; \
      SC = (quad < 3) ? sp[rr] : 0.0f; } }
#define WRITE_RBUF(B, G, SC) { \
    float* rb_ = rbase + (B) * RBUFSZ; \
    _Pragma("unroll") \
    for (int r = 0; r < 4; ++r) { int gi = lane + r * 64; int rw = gi / NGEN; \
        int cl = gi - rw * NGEN; rb_[rw * RSTRIDE + 3 + cl] = G[r]; } \
    if (lane < 32) { int gi = lane + 256; int rw = gi / NGEN; int cl = gi - rw * NGEN; \
        rb_[rw * RSTRIDE + 3 + cl] = G[4]; } \
    if (quad < 3) rb_[m * RSTRIDE + quad] = SC; }
#define ISSUE_GATHER(UID, MID, P) { \
    const float4* up_ = (const float4*)(user_table + (size_t)(UID) * EMB + quad * 8); \
    P.u0 = up_[0]; P.u1 = up_[1]; \
    const float4* mp_ = (const float4*)(movie_table + (size_t)(MID) * EMB + quad * 8); \
    P.m0 = mp_[0]; P.m1 = mp_[1]; \
    P.wu = wide_W[UID]; P.wm = wide_W[NUSERS + (MID)]; }

    if (niter > 0) {
        int t_c = gwave;
        int t_n = t_c + nwaves; if (t_n >= ntiles) t_n = t_c;

        int uid_c, mid_c, uid_n, mid_n, uid_n2, mid_n2;
        float gg_c[5], sc_c, gg_n[5], sc_n;
        Pref P_c, P_n;

        LOAD_IDS(t_c, uid_c, mid_c);
        LOAD_GENRES(t_c, gg_c, sc_c);
        ISSUE_GATHER(uid_c, mid_c, P_c);
        LOAD_IDS(t_n, uid_n, mid_n);
        WRITE_RBUF(0, gg_c, sc_c);
        uid_n2 = uid_n; mid_n2 = mid_n;
        int buf = 0;

        for (int i = 0; i < niter; ++i) {
            const float* rb = rbase + buf * RBUFSZ;
            const float4* sA = (const float4*)(rb + m * RSTRIDE + quad * 8);
            float4 a2a = sA[0], a2b = sA[1];

            const bool more = (i + 1 < niter);
            int t_n2 = t_n;
            if (more) {
                LOAD_GENRES(t_n, gg_n, sc_n);
                ISSUE_GATHER(uid_n, mid_n, P_n);
                t_n2 = t_n + nwaves; if (t_n2 >= ntiles) t_n2 = t_n;
                LOAD_IDS(t_n2, uid_n2, mid_n2);
            }

            const int base = t_c << 4;
            f32x8 vf;
            vf[0]=P_c.u0.x; vf[1]=P_c.u0.y; vf[2]=P_c.u0.z; vf[3]=P_c.u0.w;
            vf[4]=P_c.u1.x; vf[5]=P_c.u1.y; vf[6]=P_c.u1.z; vf[7]=P_c.u1.w;
            bf16x8 A0 = cvt8(vf);
            vf[0]=P_c.m0.x; vf[1]=P_c.m0.y; vf[2]=P_c.m0.z; vf[3]=P_c.m0.w;
            vf[4]=P_c.m1.x; vf[5]=P_c.m1.y; vf[6]=P_c.m1.z; vf[7]=P_c.m1.w;
            bf16x8 A1 = cvt8(vf);
            vf[0]=a2a.x; vf[1]=a2a.y; vf[2]=a2a.z; vf[3]=a2a.w;
            vf[4]=a2b.x; vf[5]=a2b.y; vf[6]=a2b.z; vf[7]=a2b.w;
            if (quad == 2) vf[5] = P_c.wu + P_c.wm + wb0;
            bf16x8 A2 = cvt8(vf);

            f32x4 accw = mfma16(A2, Bwf, (f32x4){0.f, 0.f, 0.f, 0.f});

            f32x4 acc[4];
            #pragma unroll
            for (int nt = 0; nt < 4; ++nt) {
                f32x4 c = {bias1[nt], bias1[nt], bias1[nt], bias1[nt]};
                c = mfma16(A0, B1f[0][nt], c);
                c = mfma16(A1, B1f[1][nt], c);
                c = mfma16(A2, B1f[2][nt], c);
                acc[nt] = c;
            }
            #pragma unroll
            for (int nt = 0; nt < 4; ++nt)
                #pragma unroll
                for (int r = 0; r < 4; ++r)
                    L1p[(quad * 4 + r) * L1STRIDE + nt * 16 + m] = fmaxf(acc[nt][r], 0.0f);

            bf16x8 AL2[2];
            #pragma unroll
            for (int kt = 0; kt < 2; ++kt) {
                const float4* s = (const float4*)(L1p + m * L1STRIDE + kt * 32 + quad * 8);
                float4 a = s[0], b = s[1];
                f32x8 t8; t8[0]=a.x; t8[1]=a.y; t8[2]=a.z; t8[3]=a.w;
                t8[4]=b.x; t8[5]=b.y; t8[6]=b.z; t8[7]=b.w;
                AL2[kt] = cvt8(t8);
            }

            f32x4 acc2[2];
            #pragma unroll
            for (int nt = 0; nt < 2; ++nt) {
                f32x4 c = {bias2[nt], bias2[nt], bias2[nt], bias2[nt]};
                c = mfma16(AL2[0], B2f[0][nt], c);
                c = mfma16(AL2[1], B2f[1][nt], c);
                acc2[nt] = c;
            }
            #pragma unroll
            for (int nt = 0; nt < 2; ++nt)
                #pragma unroll
                for (int r = 0; r < 4; ++r)
                    L2p[(quad * 4 + r) * L2STRIDE + nt * 16 + m] = fmaxf(acc2[nt][r], 0.0f);

            bf16x8 AL3;
            {
                const float4* s = (const float4*)(L2p + m * L2STRIDE + quad * 8);
                float4 a = s[0], b = s[1];
                f32x8 t8; t8[0]=a.x; t8[1]=a.y; t8[2]=a.z; t8[3]=a.w;
                t8[4]=b.x; t8[5]=b.y; t8[6]=b.z; t8[7]=b.w;
                AL3 = cvt8(t8);
            }

            f32x4 acc3 = mfma16(AL3, B3f, (f32x4){bias3, bias3, bias3, bias3});

            float t0 = fmaxf(acc3[0], 0.0f) * w4v + accw[0];
            float t1 = fmaxf(acc3[1], 0.0f) * w4v + accw[1];
            float t2 = fmaxf(acc3[2], 0.0f) * w4v + accw[2];
            float t3 = fmaxf(acc3[3], 0.0f) * w4v + accw[3];
            #pragma unroll
            for (int off = 1; off < 16; off <<= 1) {
                t0 += __shfl_xor(t0, off, 64);
                t1 += __shfl_xor(t1, off, 64);
                t2 += __shfl_xor(t2, off, 64);
                t3 += __shfl_xor(t3, off, 64);
            }
            if (m < 4) {
                float zv = t0;
                zv = (m == 1) ? t1 : zv;
                zv = (m == 2) ? t2 : zv;
                zv = (m == 3) ? t3 : zv;
                zv += b4v;
                const int orow = base + quad * 4 + m;
                if (orow < n) out[orow] = 1.0f / (1.0f + __expf(-zv));
            }

            if (more) {
                WRITE_RBUF(buf ^ 1, gg_n, sc_n);
                P_c = P_n;
                uid_c = uid_n; mid_c = mid_n;
                uid_n = uid_n2; mid_n = mid_n2;
                t_c = t_n; t_n = t_n2;
                buf ^= 1;
            }
        }
    }
#undef LOAD_IDS
#undef LOAD_GENRES
#undef WRITE_RBUF
#undef ISSUE_GATHER
}

extern "C" void kernel_launch(void* const* d_in, const int* in_sizes, int n_in,
                              void* d_out, int out_size, void* d_ws, size_t ws_size,
                              hipStream_t stream)
{
    const int*   user_ids   = (const int*)  d_in[0];
    const int*   movie_ids  = (const int*)  d_in[1];
    const float* gender     = (const float*)d_in[2];
    const float* age        = (const float*)d_in[3];
    const float* occupation = (const float*)d_in[4];
    const float* genres     = (const float*)d_in[5];
    const float* wide_W     = (const float*)d_in[6];
    const float* wide_b     = (const float*)d_in[7];
    const float* user_table = (const float*)d_in[8];
    const float* movie_table= (const float*)d_in[9];
    const float* W1         = (const float*)d_in[10];
    const float* b1         = (const float*)d_in[11];
    const float* W2         = (const float*)d_in[12];
    const float* b2         = (const float*)d_in[13];
    const float* W3         = (const float*)d_in[14];
    const float* b3         = (const float*)d_in[15];
    const float* W4         = (const float*)d_in[16];
    const float* b4         = (const float*)d_in[17];
    float*       out        = (float*)d_out;

    const int n = in_sizes[0];

    // workspace layout: utab | mtab | rest (all 256B-aligned)
    const size_t utab_bytes = ((size_t)NUSERS  * EMB * 2 + 255) & ~(size_t)255;
    const size_t mtab_bytes = ((size_t)NMOVIES * EMB * 2 + 255) & ~(size_t)255;
    const size_t rest_bytes = (size_t)n * RESTW * 2;
    const size_t need = utab_bytes + mtab_bytes + rest_bytes;

    if (d_ws != nullptr && ws_size >= need) {
        bf16_t* utab = (bf16_t*)d_ws;
        bf16_t* mtab = (bf16_t*)((char*)d_ws + utab_bytes);
        bf16_t* rest = (bf16_t*)((char*)d_ws + utab_bytes + mtab_bytes);

        const int gB      = (n + PREPROWS - 1) / PREPROWS;
        const int tblocks = (TAB4TOT + 255) / 256;
        prep_all<<<gB + tblocks, 256, 0, stream>>>(gender, age, occupation, genres,
                                                   user_table, movie_table,
                                                   rest, utab, mtab, n);
        wd_fwd_main<<<1024, 256, 0, stream>>>(user_ids, movie_ids, wide_W, wide_b,
                                              W1, b1, W2, b2, W3, b3, W4, b4,
                                              utab, mtab, rest, out, n);
    } else {
        wd_fwd_pipe<<<1024, 256, 0, stream>>>(user_ids, movie_ids, gender, age, occupation,
                                              genres, wide_W, wide_b, user_table, movie_table,
                                              W1, b1, W2, b2, W3, b3, W4, b4, out, n);
    }
}

// Round 5
// 216.253 us; speedup vs baseline: 1.4273x; 1.0056x over previous
//
#include <hip/hip_runtime.h>

#define NUSERS  6041
#define NMOVIES 3953
#define EMB     32
#define NGEN    18
#define H1N     64
#define H2N     32
#define H3N     16

typedef __bf16 bf16_t;
typedef bf16_t bf16x8 __attribute__((ext_vector_type(8)));
typedef bf16_t bf16x4 __attribute__((ext_vector_type(4)));
typedef float  f32x4  __attribute__((ext_vector_type(4)));
typedef float  f32x8  __attribute__((ext_vector_type(8)));

__device__ __forceinline__ f32x4 mfma16(bf16x8 a, bf16x8 b, f32x4 c) {
    return __builtin_amdgcn_mfma_f32_16x16x32_bf16(a, b, c, 0, 0, 0);
}
__device__ __forceinline__ bf16x8 cvt8(f32x8 v) {
    bf16x8 o;
    #pragma unroll
    for (int i = 0; i < 8; ++i) o[i] = (bf16_t)v[i];
    return o;
}

#define L1STRIDE 68
#define L2STRIDE 36
#define RSTRIDE  28
#define RBUFSZ   (16 * RSTRIDE)

#define TAB_U4   (NUSERS * EMB / 4)            // 48328
#define TAB_M4   (NMOVIES * EMB / 4)           // 31624
#define TAB4TOT  (TAB_U4 + TAB_M4)             // 79952
#define TABBLOCKS ((TAB4TOT + 255) / 256)      // 313

// wpack: 18 fragments x 64 lanes x 8 bf16 (frag-major, lane-ordered):
//   f 0..11  = B1f[kt][nt] (kt=f/4, nt=f%4)
//   f 12     = Bwf
//   f 13..16 = B2f[kt][nt] (kt=(f-13)/2, nt=(f-13)%2)
//   f 17     = B3f
// Layer-1 rest-fragment k-slot mapping (q=quad, j=elem):
//   (q<3, j<6) -> genre 6q+j (W1 row 67+6q+j)
//   (0,6)=gender(row 64)  (0,7)=age(row 65)
//   (1,6)=occ(row 66)     (1,7)=bias-1 slot (A2=1.0, row = b1)
//   (2,6)=wide synthetic (A2=wu+wm+wb0, W1 row = 0, Bw = 1.0)   (2,7),(q=3)=0
#define WPACK_HALF 9216        // 18*64*8 bf16
#define WPACK_BYTES 18432

// ---------------------------------------------------------------------------
// prep: embedding tables -> bf16, weights -> lane-ordered bf16 fragments
// ---------------------------------------------------------------------------
__global__ __launch_bounds__(256)
void prep_pack(const float* __restrict__ user_table,
               const float* __restrict__ movie_table,
               const float* __restrict__ W1,
               const float* __restrict__ b1,
               const float* __restrict__ W2,
               const float* __restrict__ W3,
               const float* __restrict__ wide_W,
               bf16_t* __restrict__ utab,
               bf16_t* __restrict__ mtab,
               bf16_t* __restrict__ wpack)
{
    const int t = threadIdx.x;
    const int b = blockIdx.x;

    if (b < TABBLOCKS) {
        const int u = b * 256 + t;
        if (u < TAB4TOT) {
            if (u < TAB_U4) {
                float4 v = *(const float4*)(user_table + (size_t)u * 4);
                bf16x4 o; o[0]=(bf16_t)v.x; o[1]=(bf16_t)v.y; o[2]=(bf16_t)v.z; o[3]=(bf16_t)v.w;
                *(bf16x4*)(utab + (size_t)u * 4) = o;
            } else {
                const int w = u - TAB_U4;
                float4 v = *(const float4*)(movie_table + (size_t)w * 4);
                bf16x4 o; o[0]=(bf16_t)v.x; o[1]=(bf16_t)v.y; o[2]=(bf16_t)v.z; o[3]=(bf16_t)v.w;
                *(bf16x4*)(mtab + (size_t)w * 4) = o;
            }
        }
        return;
    }

    // weight-fragment packing (single block)
    const int l  = t & 63;
    const int f0 = t >> 6;               // 4 fragments per pass
    const int m  = l & 15;
    const int q  = l >> 4;
    const float* wr = wide_W + NUSERS + NMOVIES;   // [g,a,o,genres0..17] weights

    #pragma unroll
    for (int p = 0; p < 5; ++p) {
        const int f = f0 + p * 4;
        if (f >= 18) break;
        bf16x8 frag;
        #pragma unroll
        for (int j = 0; j < 8; ++j) {
            float v = 0.0f;
            if (f < 12) {                                  // B1f[kt][nt]
                const int kt = f >> 2, nt = f & 3;
                if (kt < 2) {
                    v = W1[(kt * 32 + q * 8 + j) * H1N + nt * 16 + m];
                } else if (q < 3) {
                    if (j < 6)       v = W1[(67 + 6 * q + j) * H1N + nt * 16 + m];
                    else if (q == 0) v = W1[(64 + (j - 6)) * H1N + nt * 16 + m];
                    else if (q == 1) v = (j == 6) ? W1[66 * H1N + nt * 16 + m]
                                                 : b1[nt * 16 + m];
                    // q==2, j>=6 -> 0 (wide/pad slots)
                }
            } else if (f == 12) {                          // Bwf (row 0 only)
                if (m == 0) {
                    if (q < 3 && j < 6)        v = wr[3 + 6 * q + j];
                    else if (q == 0)           v = wr[j - 6];     // gender/age
                    else if (q == 1 && j == 6) v = wr[2];         // occ
                    else if (q == 2 && j == 6) v = 1.0f;          // wide synth
                }
            } else if (f < 17) {                           // B2f (rows permuted)
                const int kt = (f - 13) >> 1, nt = (f - 13) & 1;
                const int u = (2 * kt + (j >> 2)) * 16 + q * 4 + (j & 3);
                v = W2[u * H2N + nt * 16 + m];
            } else {                                       // B3f (rows permuted)
                const int u = (j >> 2) * 16 + q * 4 + (j & 3);
                v = W3[u * H3N + m];
            }
            frag[j] = (bf16_t)v;
        }
        *(bf16x8*)(wpack + ((size_t)f * 64 + l) * 8) = frag;
    }
}

// ---------------------------------------------------------------------------
// main: operand-swapped MFMA chain, 2 tiles (32 rows) per iteration for ILP.
// Genres/scalars read f32 directly (W1 k-rows pre-permuted to match);
// no rest buffer, no LDS, no barriers. ~190 VGPR live -> (256,2).
// ---------------------------------------------------------------------------
__global__ __launch_bounds__(256, 2)
void wd_fwd_main2(const int*   __restrict__ user_ids,
                  const int*   __restrict__ movie_ids,
                  const float* __restrict__ gender,
                  const float* __restrict__ age,
                  const float* __restrict__ occupation,
                  const float* __restrict__ genres,
                  const float* __restrict__ wide_W,
                  const float* __restrict__ wide_b,
                  const float* __restrict__ b2,
                  const float* __restrict__ b3,
                  const float* __restrict__ W4,
                  const float* __restrict__ b4,
                  const bf16_t* __restrict__ utab,
                  const bf16_t* __restrict__ mtab,
                  const bf16_t* __restrict__ wpack,
                  float*       __restrict__ out,
                  int n)
{
    const int lane = threadIdx.x & 63;
    const int m    = lane & 15;
    const int quad = lane >> 4;

    // ---- weight fragments: 18 coalesced 16B loads ----
    const bf16x8* wp = (const bf16x8*)wpack;
    bf16x8 B1f[3][4];
    #pragma unroll
    for (int kt = 0; kt < 3; ++kt)
        #pragma unroll
        for (int nt = 0; nt < 4; ++nt)
            B1f[kt][nt] = wp[(kt * 4 + nt) * 64 + lane];
    const bf16x8 Bwf = wp[12 * 64 + lane];
    bf16x8 B2f[2][2];
    #pragma unroll
    for (int kt = 0; kt < 2; ++kt)
        #pragma unroll
        for (int nt = 0; nt < 2; ++nt)
            B2f[kt][nt] = wp[(13 + kt * 2 + nt) * 64 + lane];
    const bf16x8 B3f = wp[17 * 64 + lane];

    f32x4 bias2[2], bias3, w4f;
    bias2[0] = *(const f32x4*)(b2 + quad * 4);
    bias2[1] = *(const f32x4*)(b2 + 16 + quad * 4);
    bias3    = *(const f32x4*)(b3 + quad * 4);
    w4f      = *(const f32x4*)(W4 + quad * 4);
    const float b4v = b4[0];
    const float wb0 = wide_b[0];

    const int nst   = (n + 31) >> 5;                      // 32-row supertiles
    const int gwave = (blockIdx.x * blockDim.x + threadIdx.x) >> 6;
    const int nw    = (gridDim.x * blockDim.x) >> 6;
    int niter = 0;
    if (gwave < nst) niter = (nst - gwave + nw - 1) / nw;
    if (niter == 0) return;

    int st_c = gwave;
    int st_n = st_c + nw; if (st_n >= nst) st_n = st_c;

#define GATHER(row_, uid_, mid_, A0_, A1_, A2_) {                              \
    A0_ = *(const bf16x8*)(utab + (size_t)(uid_) * EMB + quad * 8);            \
    A1_ = *(const bf16x8*)(mtab + (size_t)(mid_) * EMB + quad * 8);            \
    float2 g01 = {0.f,0.f}, g23 = {0.f,0.f}, g45 = {0.f,0.f};                  \
    float s6 = 0.f, s7 = 0.f;                                                  \
    if (quad < 3) {                                                            \
        const float* gp_ = genres + (size_t)(row_) * NGEN + quad * 6;          \
        g01 = *(const float2*)gp_;                                             \
        g23 = *(const float2*)(gp_ + 2);                                       \
        g45 = *(const float2*)(gp_ + 4);                                       \
    }                                                                          \
    if (quad == 0)      { s6 = gender[row_]; s7 = age[row_]; }                 \
    else if (quad == 1) { s6 = occupation[row_]; s7 = 1.0f; }                  \
    else if (quad == 2) { s6 = wide_W[uid_] + wide_W[NUSERS + (mid_)] + wb0; } \
    A2_[0] = (bf16_t)g01.x; A2_[1] = (bf16_t)g01.y;                            \
    A2_[2] = (bf16_t)g23.x; A2_[3] = (bf16_t)g23.y;                            \
    A2_[4] = (bf16_t)g45.x; A2_[5] = (bf16_t)g45.y;                            \
    A2_[6] = (bf16_t)s6;    A2_[7] = (bf16_t)s7; }

    // ---- prologue: current supertile fully loaded; next supertile's ids ----
    int ra = st_c * 32 + m;      if (ra >= n) ra = n - 1;
    int rb = st_c * 32 + 16 + m; if (rb >= n) rb = n - 1;
    int uidA = user_ids[ra], midA = movie_ids[ra];
    int uidB = user_ids[rb], midB = movie_ids[rb];
    bf16x8 A0a, A1a, A2a, A0b, A1b, A2b;
    GATHER(ra, uidA, midA, A0a, A1a, A2a);
    GATHER(rb, uidB, midB, A0b, A1b, A2b);
    int ran = st_n * 32 + m;      if (ran >= n) ran = n - 1;
    int rbn = st_n * 32 + 16 + m; if (rbn >= n) rbn = n - 1;
    int uidAn = user_ids[ran], midAn = movie_ids[ran];
    int uidBn = user_ids[rbn], midBn = movie_ids[rbn];

    for (int i = 0; i < niter; ++i) {
        // ---- 1. prefetch next supertile (ids loaded >=1 iter ago) ----
        const bool more = (i + 1 < niter);
        bf16x8 A0an = A0a, A1an = A1a, A2an = A2a;
        bf16x8 A0bn = A0b, A1bn = A1b, A2bn = A2b;
        int uidA2 = uidAn, midA2 = midAn, uidB2 = uidBn, midB2 = midBn;
        int st_n2 = st_n;
        if (more) {
            int ran_ = st_n * 32 + m;      if (ran_ >= n) ran_ = n - 1;
            int rbn_ = st_n * 32 + 16 + m; if (rbn_ >= n) rbn_ = n - 1;
            GATHER(ran_, uidAn, midAn, A0an, A1an, A2an);
            GATHER(rbn_, uidBn, midBn, A0bn, A1bn, A2bn);
            st_n2 = st_n + nw; if (st_n2 >= nst) st_n2 = st_n;
            int ra2 = st_n2 * 32 + m;      if (ra2 >= n) ra2 = n - 1;
            int rb2 = st_n2 * 32 + 16 + m; if (rb2 >= n) rb2 = n - 1;
            uidA2 = user_ids[ra2]; midA2 = movie_ids[ra2];
            uidB2 = user_ids[rb2]; midB2 = movie_ids[rb2];
        }

        // ---- 2. compute both tiles, interleaved (2 independent chains) ----
        const f32x4 z4 = {0.f, 0.f, 0.f, 0.f};
        f32x4 accwA = mfma16(Bwf, A2a, z4);
        f32x4 accwB = mfma16(Bwf, A2b, z4);

        f32x4 aA[4], aB[4];
        #pragma unroll
        for (int nt = 0; nt < 4; ++nt) {
            aA[nt] = mfma16(B1f[2][nt], A2a, z4);
            aB[nt] = mfma16(B1f[2][nt], A2b, z4);
        }
        #pragma unroll
        for (int nt = 0; nt < 4; ++nt) {
            aA[nt] = mfma16(B1f[1][nt], A1a, aA[nt]);
            aB[nt] = mfma16(B1f[1][nt], A1b, aB[nt]);
        }
        #pragma unroll
        for (int nt = 0; nt < 4; ++nt) {
            aA[nt] = mfma16(B1f[0][nt], A0a, aA[nt]);
            aB[nt] = mfma16(B1f[0][nt], A0b, aB[nt]);
        }

        bf16x8 L2a[2], L2b[2];
        #pragma unroll
        for (int kt = 0; kt < 2; ++kt)
            #pragma unroll
            for (int r = 0; r < 4; ++r) {
                L2a[kt][r]     = (bf16_t)fmaxf(aA[2 * kt][r],     0.f);
                L2a[kt][4 + r] = (bf16_t)fmaxf(aA[2 * kt + 1][r], 0.f);
                L2b[kt][r]     = (bf16_t)fmaxf(aB[2 * kt][r],     0.f);
                L2b[kt][4 + r] = (bf16_t)fmaxf(aB[2 * kt + 1][r], 0.f);
            }

        f32x4 c2A[2], c2B[2];
        #pragma unroll
        for (int nt = 0; nt < 2; ++nt) {
            c2A[nt] = mfma16(B2f[1][nt], L2a[1], mfma16(B2f[0][nt], L2a[0], bias2[nt]));
            c2B[nt] = mfma16(B2f[1][nt], L2b[1], mfma16(B2f[0][nt], L2b[0], bias2[nt]));
        }

        bf16x8 L3a, L3b;
        #pragma unroll
        for (int r = 0; r < 4; ++r) {
            L3a[r]     = (bf16_t)fmaxf(c2A[0][r], 0.f);
            L3a[4 + r] = (bf16_t)fmaxf(c2A[1][r], 0.f);
            L3b[r]     = (bf16_t)fmaxf(c2B[0][r], 0.f);
            L3b[4 + r] = (bf16_t)fmaxf(c2B[1][r], 0.f);
        }

        f32x4 c3A = mfma16(B3f, L3a, bias3);
        f32x4 c3B = mfma16(B3f, L3b, bias3);

        float pA = fmaxf(c3A[0], 0.f) * w4f[0] + fmaxf(c3A[1], 0.f) * w4f[1]
                 + fmaxf(c3A[2], 0.f) * w4f[2] + fmaxf(c3A[3], 0.f) * w4f[3];
        float pB = fmaxf(c3B[0], 0.f) * w4f[0] + fmaxf(c3B[1], 0.f) * w4f[1]
                 + fmaxf(c3B[2], 0.f) * w4f[2] + fmaxf(c3B[3], 0.f) * w4f[3];
        pA += __shfl_xor(pA, 16, 64);  pA += __shfl_xor(pA, 32, 64);
        pB += __shfl_xor(pB, 16, 64);  pB += __shfl_xor(pB, 32, 64);

        if (lane < 16) {                 // quad-0 reg 0 holds the wide row
            const int base = st_c << 5;
            const int oa = base + lane, ob = base + 16 + lane;
            const float zA = pA + accwA[0] + b4v;
            const float zB = pB + accwB[0] + b4v;
            if (oa < n) out[oa] = 1.0f / (1.0f + __expf(-zA));
            if (ob < n) out[ob] = 1.0f / (1.0f + __expf(-zB));
        }

        // ---- 3. rotate pipeline ----
        if (more) {
            A0a = A0an; A1a = A1an; A2a = A2an;
            A0b = A0bn; A1b = A1bn; A2b = A2bn;
            uidAn = uidA2; midAn = midA2; uidBn = uidB2; midBn = midB2;
            st_c = st_n; st_n = st_n2;
        }
    }
#undef GATHER
}

// ---------------------------------------------------------------------------
// fallback: original verified kernel (used only if workspace is too small)
// ---------------------------------------------------------------------------
struct Pref {
    float4 u0, u1, m0, m1;
    float  wu, wm;
};

__global__ __launch_bounds__(256)
void wd_fwd_pipe(const int*   __restrict__ user_ids,
                 const int*   __restrict__ movie_ids,
                 const float* __restrict__ gender,
                 const float* __restrict__ age,
                 const float* __restrict__ occupation,
                 const float* __restrict__ genres,
                 const float* __restrict__ wide_W,
                 const float* __restrict__ wide_b,
                 const float* __restrict__ user_table,
                 const float* __restrict__ movie_table,
                 const float* __restrict__ W1,
                 const float* __restrict__ b1,
                 const float* __restrict__ W2,
                 const float* __restrict__ b2,
                 const float* __restrict__ W3,
                 const float* __restrict__ b3,
                 const float* __restrict__ W4,
                 const float* __restrict__ b4,
                 float*       __restrict__ out,
                 int n)
{
    const int lane = threadIdx.x & 63;
    const int wib  = threadIdx.x >> 6;
    const int m    = lane & 15;
    const int quad = lane >> 4;

    __shared__ float lds_rest[4][2 * RBUFSZ];
    __shared__ float lds1[4][16 * L1STRIDE];
    __shared__ float lds2[4][16 * L2STRIDE];
    float* __restrict__ rbase = lds_rest[wib];
    float* __restrict__ L1p   = lds1[wib];
    float* __restrict__ L2p   = lds2[wib];

    for (int k = lane; k < 2 * RBUFSZ; k += 64) rbase[k] = 0.0f;

    bf16x8 B1f[3][4];
    #pragma unroll
    for (int kt = 0; kt < 3; ++kt)
        #pragma unroll
        for (int nt = 0; nt < 4; ++nt) {
            bf16x8 f;
            #pragma unroll
            for (int j = 0; j < 8; ++j) {
                const int k  = kt * 32 + quad * 8 + j;
                const float v = (k < 85) ? W1[k * H1N + nt * 16 + m] : 0.0f;
                f[j] = (bf16_t)v;
            }
            B1f[kt][nt] = f;
        }
    bf16x8 Bwf;
    {
        const float* wr = wide_W + NUSERS + NMOVIES;
        #pragma unroll
        for (int j = 0; j < 8; ++j) {
            const int k = 64 + quad * 8 + j;
            float v = 0.0f;
            if (m == 0) { if (k < 85) v = wr[k - 64]; else if (k == 85) v = 1.0f; }
            Bwf[j] = (bf16_t)v;
        }
    }
    bf16x8 B2f[2][2];
    #pragma unroll
    for (int kt = 0; kt < 2; ++kt)
        #pragma unroll
        for (int nt = 0; nt < 2; ++nt) {
            bf16x8 f;
            #pragma unroll
            for (int j = 0; j < 8; ++j)
                f[j] = (bf16_t)W2[(kt * 32 + quad * 8 + j) * H2N + nt * 16 + m];
            B2f[kt][nt] = f;
        }
    bf16x8 B3f;
    #pragma unroll
    for (int j = 0; j < 8; ++j) B3f[j] = (bf16_t)W3[(quad * 8 + j) * H3N + m];

    float bias1[4], bias2[2];
    #pragma unroll
    for (int nt = 0; nt < 4; ++nt) bias1[nt] = b1[nt * 16 + m];
    #pragma unroll
    for (int nt = 0; nt < 2; ++nt) bias2[nt] = b2[nt * 16 + m];
    const float bias3 = b3[m];
    const float w4v   = W4[m];
    const float b4v   = b4[0];
    const float wb0   = wide_b[0];

    const int ntiles = (n + 15) >> 4;
    const int gwave  = blockIdx.x * 4 + wib;
    const int nwaves = gridDim.x * 4;
    int niter = 0;
    if (gwave < ntiles) niter = (ntiles - gwave + nwaves - 1) / nwaves;
    const long gmax = (long)n * NGEN - 1;

#define LOAD_IDS(tt, U, M) { int rr = (tt) * 16 + m; rr = rr < n ? rr : n - 1; \
                             U = user_ids[rr]; M = movie_ids[rr]; }
#define LOAD_GENRES(tt, G, SC) { \
    const long gb = (long)(tt) * (16 * NGEN); \
    _Pragma("unroll") \
    for (int r = 0; r < 4; ++r) { long idx = gb + lane + r * 64; \
        idx = idx < gmax ? idx : gmax; G[r] = genres[idx]; } \
    { long idx = gb + lane + 256; idx = idx < gmax ? idx : gmax; \
      G[4] = (lane < 32) ? genres[idx] : 0.0f; } \
    { int rr = (tt) * 16 + m; rr = rr < n ? rr : n - 1; \
      const float* sp = (quad == 0) ? gender : (quad == 1) ? age : occupation; \
      SC = (quad < 3) ? sp[rr] : 0.0f; } }
#define WRITE_RBUF(B, G, SC) { \
    float* rb_ = rbase + (B) * RBUFSZ; \
    _Pragma("unroll") \
    for (int r = 0; r < 4; ++r) { int gi = lane + r * 64; int rw = gi / NGEN; \
        int cl = gi - rw * NGEN; rb_[rw * RSTRIDE + 3 + cl] = G[r]; } \
    if (lane < 32) { int gi = lane + 256; int rw = gi / NGEN; int cl = gi - rw * NGEN; \
        rb_[rw * RSTRIDE + 3 + cl] = G[4]; } \
    if (quad < 3) rb_[m * RSTRIDE + quad] = SC; }
#define ISSUE_GATHER(UID, MID, P) { \
    const float4* up_ = (const float4*)(user_table + (size_t)(UID) * EMB + quad * 8); \
    P.u0 = up_[0]; P.u1 = up_[1]; \
    const float4* mp_ = (const float4*)(movie_table + (size_t)(MID) * EMB + quad * 8); \
    P.m0 = mp_[0]; P.m1 = mp_[1]; \
    P.wu = wide_W[UID]; P.wm = wide_W[NUSERS + (MID)]; }

    if (niter > 0) {
        int t_c = gwave;
        int t_n = t_c + nwaves; if (t_n >= ntiles) t_n = t_c;

        int uid_c, mid_c, uid_n, mid_n, uid_n2, mid_n2;
        float gg_c[5], sc_c, gg_n[5], sc_n;
        Pref P_c, P_n;

        LOAD_IDS(t_c, uid_c, mid_c);
        LOAD_GENRES(t_c, gg_c, sc_c);
        ISSUE_GATHER(uid_c, mid_c, P_c);
        LOAD_IDS(t_n, uid_n, mid_n);
        WRITE_RBUF(0, gg_c, sc_c);
        uid_n2 = uid_n; mid_n2 = mid_n;
        int buf = 0;

        for (int i = 0; i < niter; ++i) {
            const float* rb = rbase + buf * RBUFSZ;
            const float4* sA = (const float4*)(rb + m * RSTRIDE + quad * 8);
            float4 a2a = sA[0], a2b = sA[1];

            const bool more = (i + 1 < niter);
            int t_n2 = t_n;
            if (more) {
                LOAD_GENRES(t_n, gg_n, sc_n);
                ISSUE_GATHER(uid_n, mid_n, P_n);
                t_n2 = t_n + nwaves; if (t_n2 >= ntiles) t_n2 = t_n;
                LOAD_IDS(t_n2, uid_n2, mid_n2);
            }

            const int base = t_c << 4;
            f32x8 vf;
            vf[0]=P_c.u0.x; vf[1]=P_c.u0.y; vf[2]=P_c.u0.z; vf[3]=P_c.u0.w;
            vf[4]=P_c.u1.x; vf[5]=P_c.u1.y; vf[6]=P_c.u1.z; vf[7]=P_c.u1.w;
            bf16x8 A0 = cvt8(vf);
            vf[0]=P_c.m0.x; vf[1]=P_c.m0.y; vf[2]=P_c.m0.z; vf[3]=P_c.m0.w;
            vf[4]=P_c.m1.x; vf[5]=P_c.m1.y; vf[6]=P_c.m1.z; vf[7]=P_c.m1.w;
            bf16x8 A1 = cvt8(vf);
            vf[0]=a2a.x; vf[1]=a2a.y; vf[2]=a2a.z; vf[3]=a2a.w;
            vf[4]=a2b.x; vf[5]=a2b.y; vf[6]=a2b.z; vf[7]=a2b.w;
            if (quad == 2) vf[5] = P_c.wu + P_c.wm + wb0;
            bf16x8 A2 = cvt8(vf);

            f32x4 accw = mfma16(A2, Bwf, (f32x4){0.f, 0.f, 0.f, 0.f});

            f32x4 acc[4];
            #pragma unroll
            for (int nt = 0; nt < 4; ++nt) {
                f32x4 c = {bias1[nt], bias1[nt], bias1[nt], bias1[nt]};
                c = mfma16(A0, B1f[0][nt], c);
                c = mfma16(A1, B1f[1][nt], c);
                c = mfma16(A2, B1f[2][nt], c);
                acc[nt] = c;
            }
            #pragma unroll
            for (int nt = 0; nt < 4; ++nt)
                #pragma unroll
                for (int r = 0; r < 4; ++r)
                    L1p[(quad * 4 + r) * L1STRIDE + nt * 16 + m] = fmaxf(acc[nt][r], 0.0f);

            bf16x8 AL2[2];
            #pragma unroll
            for (int kt = 0; kt < 2; ++kt) {
                const float4* s = (const float4*)(L1p + m * L1STRIDE + kt * 32 + quad * 8);
                float4 a = s[0], b = s[1];
                f32x8 t8; t8[0]=a.x; t8[1]=a.y; t8[2]=a.z; t8[3]=a.w;
                t8[4]=b.x; t8[5]=b.y; t8[6]=b.z; t8[7]=b.w;
                AL2[kt] = cvt8(t8);
            }

            f32x4 acc2[2];
            #pragma unroll
            for (int nt = 0; nt < 2; ++nt) {
                f32x4 c = {bias2[nt], bias2[nt], bias2[nt], bias2[nt]};
                c = mfma16(AL2[0], B2f[0][nt], c);
                c = mfma16(AL2[1], B2f[1][nt], c);
                acc2[nt] = c;
            }
            #pragma unroll
            for (int nt = 0; nt < 2; ++nt)
                #pragma unroll
                for (int r = 0; r < 4; ++r)
                    L2p[(quad * 4 + r) * L2STRIDE + nt * 16 + m] = fmaxf(acc2[nt][r], 0.0f);

            bf16x8 AL3;
            {
                const float4* s = (const float4*)(L2p + m * L2STRIDE + quad * 8);
                float4 a = s[0], b = s[1];
                f32x8 t8; t8[0]=a.x; t8[1]=a.y; t8[2]=a.z; t8[3]=a.w;
                t8[4]=b.x; t8[5]=b.y; t8[6]=b.z; t8[7]=b.w;
                AL3 = cvt8(t8);
            }

            f32x4 acc3 = mfma16(AL3, B3f, (f32x4){bias3, bias3, bias3, bias3});

            float t0 = fmaxf(acc3[0], 0.0f) * w4v + accw[0];
            float t1 = fmaxf(acc3[1], 0.0f) * w4v + accw[1];
            float t2 = fmaxf(acc3[2], 0.0f) * w4v + accw[2];
            float t3 = fmaxf(acc3[3], 0.0f) * w4v + accw[3];
            #pragma unroll
            for (int off = 1; off < 16; off <<= 1) {
                t0 += __shfl_xor(t0, off, 64);
                t1 += __shfl_xor(t1, off, 64);
                t2 += __shfl_xor(t2, off, 64);
                t3 += __shfl_xor(t3, off, 64);
            }
            if (m < 4) {
                float zv = t0;
                zv = (m == 1) ? t1 : zv;
                zv = (m == 2) ? t2 : zv;
                zv = (m == 3) ? t3 : zv;
                zv += b4v;
                const int orow = base + quad * 4 + m;
                if (orow < n) out[orow] = 1.0f / (1.0f + __expf(-zv));
            }

            if (more) {
                WRITE_RBUF(buf ^ 1, gg_n, sc_n);
                P_c = P_n;
                uid_c = uid_n; mid_c = mid_n;
                uid_n = uid_n2; mid_n = mid_n2;
                t_c = t_n; t_n = t_n2;
                buf ^= 1;
            }
        }
    }
#undef LOAD_IDS
#undef LOAD_GENRES
#undef WRITE_RBUF
#undef ISSUE_GATHER
}

extern "C" void kernel_launch(void* const* d_in, const int* in_sizes, int n_in,
                              void* d_out, int out_size, void* d_ws, size_t ws_size,
                              hipStream_t stream)
{
    const int*   user_ids   = (const int*)  d_in[0];
    const int*   movie_ids  = (const int*)  d_in[1];
    const float* gender     = (const float*)d_in[2];
    const float* age        = (const float*)d_in[3];
    const float* occupation = (const float*)d_in[4];
    const float* genres     = (const float*)d_in[5];
    const float* wide_W     = (const float*)d_in[6];
    const float* wide_b     = (const float*)d_in[7];
    const float* user_table = (const float*)d_in[8];
    const float* movie_table= (const float*)d_in[9];
    const float* W1         = (const float*)d_in[10];
    const float* b1         = (const float*)d_in[11];
    const float* W2         = (const float*)d_in[12];
    const float* b2         = (const float*)d_in[13];
    const float* W3         = (const float*)d_in[14];
    const float* b3         = (const float*)d_in[15];
    const float* W4         = (const float*)d_in[16];
    const float* b4         = (const float*)d_in[17];
    float*       out        = (float*)d_out;

    const int n = in_sizes[0];

    // workspace layout: utab | mtab | wpack (256B-aligned)
    const size_t utab_bytes = ((size_t)NUSERS  * EMB * 2 + 255) & ~(size_t)255;
    const size_t mtab_bytes = ((size_t)NMOVIES * EMB * 2 + 255) & ~(size_t)255;
    const size_t need = utab_bytes + mtab_bytes + WPACK_BYTES;

    if (d_ws != nullptr && ws_size >= need) {
        bf16_t* utab  = (bf16_t*)d_ws;
        bf16_t* mtab  = (bf16_t*)((char*)d_ws + utab_bytes);
        bf16_t* wpack = (bf16_t*)((char*)d_ws + utab_bytes + mtab_bytes);

        prep_pack<<<TABBLOCKS + 1, 256, 0, stream>>>(user_table, movie_table,
                                                     W1, b1, W2, W3, wide_W,
                                                     utab, mtab, wpack);
        wd_fwd_main2<<<1024, 256, 0, stream>>>(user_ids, movie_ids,
                                               gender, age, occupation, genres,
                                               wide_W, wide_b, b2, b3, W4, b4,
                                               utab, mtab, wpack, out, n);
    } else {
        wd_fwd_pipe<<<1024, 256, 0, stream>>>(user_ids, movie_ids, gender, age, occupation,
                                              genres, wide_W, wide_b, user_table, movie_table,
                                              W1, b1, W2, b2, W3, b3, W4, b4, out, n);
    }
}